// Round 19
// baseline (340.306 us; speedup 1.0000x reference)
//
#include <hip/hip_runtime.h>
#include <hip/hip_bf16.h>

// Problem constants (match reference)
#define NN 100000   // nodes
#define NE 640000   // edges
#define NG 64       // graphs
#define BN_EPS 1e-5f

#define BS 256      // block size
#define PNPB 256    // nodes per block in pool
#define CAP 32      // fixed CSR slots per row (P(indeg>=32) ~ 1e-9; wrap-guarded)

// fused1: interleaved heterogeneous grid, 4 scatter : 5 gemm per 9-block group
// (R15-proven). R17 lesson: no last-block-ticket head fusion (fences cost 27us).
#define NB_SCAT 1250                 // cdiv(NE, 512)
#define NB_G1   1563
#define NB_F1   (313 * 9)            // 2817

typedef __attribute__((ext_vector_type(8))) unsigned short ushort8_t;
typedef __attribute__((ext_vector_type(4))) unsigned short ushort4_t;
typedef __attribute__((ext_vector_type(8))) short bf16x8_t;    // MFMA A/B frag (4 VGPR)
typedef __attribute__((ext_vector_type(4))) float floatx4_t;   // MFMA C/D frag

static inline int cdiv(long long a, int b) { return (int)((a + b - 1) / b); }

__device__ __forceinline__ float bf2f(unsigned short u) {
    union { unsigned int i; float f; } c; c.i = ((unsigned int)u) << 16; return c.f;
}
__device__ __forceinline__ unsigned short f2bf(float f) {   // RNE
    unsigned int u = __float_as_uint(f);
    u += 0x7fffu + ((u >> 16) & 1u);
    return (unsigned short)(u >> 16);
}

// ---- MLP gather core: 4 neighbor indices per int4 col load, predicated 4-wide
// load phase (independent gathers), then accumulate. R18 props had 2-deep
// dependent chains; this doubles outstanding gathers per thread. ----
template <int FW>
__device__ __forceinline__ void gather_accum(
        const unsigned short* __restrict__ Src, const int* __restrict__ col,
        const float* __restrict__ rdeg, int rowbase, int cnt, float di, int c,
        float acc[8]) {
    for (int p0 = 0; p0 < cnt; p0 += 4) {
        int4 cs = *(const int4*)(col + rowbase + p0);   // 16B-aligned (CAP=32, p0%4==0)
        int srcs[4] = {cs.x, cs.y, cs.z, cs.w};
        float w[4];
        ushort8_t u[4];
#pragma unroll
        for (int j = 0; j < 4; j++) {
            w[j] = 0.f;
            u[j] = (ushort8_t){0, 0, 0, 0, 0, 0, 0, 0};
            if (p0 + j < cnt) {                          // predication: never deref poison slots
                int s = srcs[j];
                w[j] = di * rdeg[s];
                u[j] = *(const ushort8_t*)(Src + (size_t)s * FW + c);
            }
        }
#pragma unroll
        for (int j = 0; j < 4; j++)
#pragma unroll
            for (int q = 0; q < 8; q++) acc[q] = fmaf(w[j], bf2f(u[j][q]), acc[q]);
    }
}

// ---- prepB piece: Bcat = [W2 | W1 | W0-W2] (FI x 3FO) in MFMA B-fragment layout ----
template <int FI, int FO>
__device__ __forceinline__ void prep_one(const float* __restrict__ W,
                                         unsigned short* __restrict__ Bfrag, int id) {
    constexpr int NS = FI / 32;
    int lane = id & 63;
    int s = (id >> 6) % NS;
    int t = (id >> 6) / NS;
    int n = t * 16 + (lane & 15);
    int kbase = s * 32 + (lane >> 4) * 8;
    int sec = n / FO;        // 0 -> W2, 1 -> W1, 2 -> W0 - W2
    int nc  = n % FO;
    ushort8_t out;
#pragma unroll
    for (int j = 0; j < 8; j++) {
        int k = kbase + j;
        float v;
        if (sec == 0)      v = W[(size_t)(2 * FI + k) * FO + nc];
        else if (sec == 1) v = W[(size_t)(1 * FI + k) * FO + nc];
        else               v = W[(size_t)(0 * FI + k) * FO + nc]
                             - W[(size_t)(2 * FI + k) * FO + nc];
        out[j] = f2bf(v);
    }
    *(ushort8_t*)(Bfrag + (size_t)id * 8) = out;
}

// Separate launch, stream-ordered BEFORE any consumer of Bf1/2/3 (R13 race lesson).
__global__ void prepB_all_kernel(const float* __restrict__ W1, const float* __restrict__ W2,
                                 const float* __restrict__ W3,
                                 unsigned short* __restrict__ Bf1,
                                 unsigned short* __restrict__ Bf2,
                                 unsigned short* __restrict__ Bf3) {
    int id = blockIdx.x * blockDim.x + threadIdx.x;
    if (id < 3072)      prep_one<128, 64>(W1, Bf1, id);            // 12*4*64
    else if (id < 3840) prep_one<64, 32>(W2, Bf2, id - 3072);      //  6*2*64
    else if (id < 4032) prep_one<32, 16>(W3, Bf3, id - 3840);      //  3*1*64
}

// ---- fused1: interleaved [scatter | gemm layer-1], NO LDS ----
__global__ __launch_bounds__(256) void fused1_kernel(
        const int* __restrict__ src, const int* __restrict__ dst,
        int* __restrict__ fill, int* __restrict__ deg_o, int* __restrict__ col,
        const unsigned short* __restrict__ Bf1,
        const float* __restrict__ x, unsigned short* __restrict__ Tbf,
        unsigned short* __restrict__ Sbf, unsigned short* __restrict__ Ubf,
        int E, int N) {
    const int g = blockIdx.x / 9;
    const int r = blockIdx.x % 9;
    if (r < 4) {
        // ------- scatter: 2 edges/thread (R15-proven) -------
        int sid = g * 4 + r;
        if (sid >= NB_SCAT) return;
        int e0 = (sid * 256 + threadIdx.x) * 2;
#pragma unroll
        for (int q = 0; q < 2; q++) {
            int e = e0 + q;
            if (e < E) {
                int s = src[e], d = dst[e];
                if (s != d) {
                    atomicAdd(&deg_o[s], 1);
                    int pos = atomicAdd(&fill[d], 1) & (CAP - 1);   // wrap guard
                    col[(size_t)d * CAP + pos] = s;
                }
            }
        }
        return;
    }
    // ------- gemm layer-1 path (direct-global B, latency hides in atomic shadow) -------
    int gblk = g * 5 + (r - 4);
    if (gblk >= NB_G1) return;
    constexpr int NT = 12;   // 3*64/16
    constexpr int NS = 4;    // 128/32
    const int lane = threadIdx.x & 63;
    const int wave = threadIdx.x >> 6;
    const int m0   = gblk * 64 + wave * 16;
    const int quad = lane >> 4;
    const int mrow = m0 + (lane & 15);

    floatx4_t acc[NT];
#pragma unroll
    for (int t = 0; t < NT; t++) acc[t] = (floatx4_t){0.f, 0.f, 0.f, 0.f};

#pragma unroll
    for (int s = 0; s < NS; s++) {
        bf16x8_t a;
        if (mrow < N) {
            const float* ap = x + (size_t)mrow * 128 + s * 32 + quad * 8;
            float4 a0 = *(const float4*)(ap);
            float4 a1 = *(const float4*)(ap + 4);
            a[0] = (short)f2bf(a0.x); a[1] = (short)f2bf(a0.y);
            a[2] = (short)f2bf(a0.z); a[3] = (short)f2bf(a0.w);
            a[4] = (short)f2bf(a1.x); a[5] = (short)f2bf(a1.y);
            a[6] = (short)f2bf(a1.z); a[7] = (short)f2bf(a1.w);
        } else {
            a = (bf16x8_t){0, 0, 0, 0, 0, 0, 0, 0};
        }
#pragma unroll
        for (int t = 0; t < NT; t++) {
            bf16x8_t b = *(const bf16x8_t*)(Bf1 + ((size_t)(t * NS + s) * 64 + lane) * 8);
            acc[t] = __builtin_amdgcn_mfma_f32_16x16x32_bf16(a, b, acc[t], 0, 0, 0);
        }
    }
    // C/D layout: col = lane&15, row = quad*4 + reg   [verified m89/m91]
#pragma unroll
    for (int t = 0; t < NT; t++) {
        int n   = t * 16 + (lane & 15);
        int sec = (t * 16) / 64;
        int nc  = n % 64;
#pragma unroll
        for (int r2 = 0; r2 < 4; r2++) {
            int m = m0 + quad * 4 + r2;
            if (m >= N) continue;
            unsigned short v = f2bf(acc[t][r2]);
            size_t o = (size_t)m * 64 + nc;
            if (sec == 0)      Ubf[o] = v;
            else if (sec == 1) Tbf[o] = v;
            else               Sbf[o] = v;
        }
    }
}

// ---- rdeg: rsqrt table so props do 1 mul/edge ----
__global__ void rdeg_kernel(const int* __restrict__ deg_o, float* __restrict__ rdeg, int N) {
    int i = blockIdx.x * blockDim.x + threadIdx.x;
    if (i < N) {
        int d = deg_o[i];
        rdeg[i] = (d > 0) ? rsqrtf((float)d) : 0.0f;
    }
}

// ---- propA8: Obf[i] = bf16( T[i] + 2 * sum_p w(p)*Ubf[col[p]] ), 4-wide MLP gathers ----
template <int FO>
__global__ void propA8_kernel(const unsigned short* __restrict__ Ubf,
                              const unsigned short* __restrict__ Tbf,
                              const int* __restrict__ fill, const float* __restrict__ rdeg,
                              const int* __restrict__ col,
                              unsigned short* __restrict__ Obf, int N) {
    constexpr int PER = FO / 8;
    unsigned idx = blockIdx.x * blockDim.x + threadIdx.x;
    if (idx >= (unsigned)N * PER) return;
    int i = idx / PER;
    int c = (idx & (PER - 1)) * 8;
    int cnt = min(fill[i], CAP);
    float di = -rdeg[i];
    float acc[8] = {0.f, 0.f, 0.f, 0.f, 0.f, 0.f, 0.f, 0.f};
    gather_accum<FO>(Ubf, col, rdeg, i * CAP, cnt, di, c, acc);
    ushort8_t tv = *(const ushort8_t*)(Tbf + (size_t)i * FO + c);
    ushort8_t o;
#pragma unroll
    for (int j = 0; j < 8; j++) o[j] = f2bf(bf2f(tv[j]) + 2.f * acc[j]);
    *(ushort8_t*)(Obf + (size_t)i * FO + c) = o;
}

// ---- propCG<FI,FO>: fused [propC layer-k epilogue -> LDS h] + [gemm FI->FO] ----
template <int FI, int FO>
__global__ __launch_bounds__(256) void propCG_kernel(
        const unsigned short* __restrict__ Bbf,   // gather source (propA out), width FI
        const unsigned short* __restrict__ Sbf,   // local S term, width FI
        const int* __restrict__ fill, const float* __restrict__ rdeg,
        const int* __restrict__ col,
        const float* __restrict__ b, const float* __restrict__ g,
        const float* __restrict__ be, const float* __restrict__ m,
        const float* __restrict__ vv,
        const unsigned short* __restrict__ Bfrag,  // FI->FO fragments
        unsigned short* __restrict__ Tout, unsigned short* __restrict__ Sout,
        unsigned short* __restrict__ Uout, int N) {
    constexpr int PER = FI / 8;
    constexpr int NT = 3 * FO / 16;
    constexpr int NS = FI / 32;
    constexpr int NFRAG = NT * NS;
    constexpr int HST = FI + 8;     // h_lds row stride (shorts)
    __shared__ ushort8_t bl[NFRAG * 64];
    __shared__ unsigned short h_lds[64 * HST];

    for (int q = threadIdx.x; q < NFRAG * 64; q += 256)
        bl[q] = ((const ushort8_t*)Bfrag)[q];

    const int m0 = blockIdx.x * 64;

    // ---- phase 1: propC for rows m0..m0+63 -> h_lds ----
    for (int w = threadIdx.x; w < 64 * PER; w += 256) {
        int ii = w / PER;
        int i  = m0 + ii;
        int c  = (w % PER) * 8;
        ushort8_t o = (ushort8_t){0, 0, 0, 0, 0, 0, 0, 0};
        if (i < N) {
            int cnt = min(fill[i], CAP);
            float di = -rdeg[i];
            float acc[8] = {0.f, 0.f, 0.f, 0.f, 0.f, 0.f, 0.f, 0.f};
            gather_accum<FI>(Bbf, col, rdeg, i * CAP, cnt, di, c, acc);
            ushort8_t sv = *(const ushort8_t*)(Sbf + (size_t)i * FI + c);
#pragma unroll
            for (int j = 0; j < 8; j++) {
                int f = c + j;
                float A = g[f] * rsqrtf(vv[f] + BN_EPS);
                float B = be[f] - (m[f] - b[f]) * A;
                float y = (bf2f(sv[j]) + acc[j]) * A + B;
                y = y > 0.0f ? y : 0.01f * y;
                o[j] = f2bf(y);
            }
        }
        *(ushort8_t*)&h_lds[ii * HST + c] = o;
    }
    __syncthreads();

    // ---- phase 2: gemm FI->FO, A from h_lds ----
    const int lane = threadIdx.x & 63;
    const int wave = threadIdx.x >> 6;
    const int quad = lane >> 4;
    const int mloc = wave * 16 + (lane & 15);

    floatx4_t acc[NT];
#pragma unroll
    for (int t = 0; t < NT; t++) acc[t] = (floatx4_t){0.f, 0.f, 0.f, 0.f};

#pragma unroll
    for (int s = 0; s < NS; s++) {
        bf16x8_t a = *(const bf16x8_t*)&h_lds[mloc * HST + s * 32 + quad * 8];
#pragma unroll
        for (int t = 0; t < NT; t++) {
            bf16x8_t bfr = *(const bf16x8_t*)&bl[(t * NS + s) * 64 + lane];
            acc[t] = __builtin_amdgcn_mfma_f32_16x16x32_bf16(a, bfr, acc[t], 0, 0, 0);
        }
    }
#pragma unroll
    for (int t = 0; t < NT; t++) {
        int n   = t * 16 + (lane & 15);
        int sec = (t * 16) / FO;
        int nc  = n % FO;
#pragma unroll
        for (int r = 0; r < 4; r++) {
            int mm = m0 + wave * 16 + quad * 4 + r;
            if (mm >= N) continue;
            unsigned short v = f2bf(acc[t][r]);
            size_t o = (size_t)mm * FO + nc;
            if (sec == 0)      Uout[o] = v;
            else if (sec == 1) Tout[o] = v;
            else               Sout[o] = v;
        }
    }
}

// ---- poolC: fused [propC layer-3 (w16) -> LDS h3] + [mean pool] ----
__global__ __launch_bounds__(256) void poolC_kernel(
        const unsigned short* __restrict__ Bbf,   // propA<16> output
        const unsigned short* __restrict__ Sbf,   // S3
        const int* __restrict__ fill, const float* __restrict__ rdeg,
        const int* __restrict__ col,
        const float* __restrict__ b, const float* __restrict__ g,
        const float* __restrict__ be, const float* __restrict__ m,
        const float* __restrict__ vv,
        const int* __restrict__ batch,
        float* __restrict__ pool, float* __restrict__ cnt, int N) {
    __shared__ unsigned short h_lds[PNPB * 16];   // 8 KB
    __shared__ float sp[NG * 16];
    __shared__ float sc[NG];
    const int t = threadIdx.x;
    for (int i = t; i < NG * 16; i += 256) sp[i] = 0.f;
    for (int i = t; i < NG; i += 256) sc[i] = 0.f;

    const int base = blockIdx.x * PNPB;
    // ---- phase 1: propC<16> for rows base..base+255 -> h_lds ----
    for (int w = t; w < PNPB * 2; w += 256) {
        int ii = w >> 1;
        int i  = base + ii;
        int c  = (w & 1) * 8;
        ushort8_t o = (ushort8_t){0, 0, 0, 0, 0, 0, 0, 0};
        if (i < N) {
            int cnt2 = min(fill[i], CAP);
            float di = -rdeg[i];
            float acc[8] = {0.f, 0.f, 0.f, 0.f, 0.f, 0.f, 0.f, 0.f};
            gather_accum<16>(Bbf, col, rdeg, i * CAP, cnt2, di, c, acc);
            ushort8_t sv = *(const ushort8_t*)(Sbf + (size_t)i * 16 + c);
#pragma unroll
            for (int j = 0; j < 8; j++) {
                int f = c + j;
                float A = g[f] * rsqrtf(vv[f] + BN_EPS);
                float B = be[f] - (m[f] - b[f]) * A;
                float y = (bf2f(sv[j]) + acc[j]) * A + B;
                y = y > 0.0f ? y : 0.01f * y;
                o[j] = f2bf(y);
            }
        }
        *(ushort8_t*)&h_lds[ii * 16 + c] = o;
    }
    __syncthreads();

    // ---- phase 2: pool from LDS ----
    const int f4 = (t & 3) * 4;      // feature quad
    const int nl = t >> 2;           // node lane 0..63
    const int nEnd = min(base + PNPB, N);
    float4 acc = make_float4(0.f, 0.f, 0.f, 0.f);
    float cacc = 0.f;
    int gcur = -1;
    for (int n = base + nl; n < nEnd; n += 64) {
        int gi = batch[n];
        if (gi != gcur) {
            if (gcur >= 0) {
                atomicAdd(&sp[gcur * 16 + f4 + 0], acc.x);
                atomicAdd(&sp[gcur * 16 + f4 + 1], acc.y);
                atomicAdd(&sp[gcur * 16 + f4 + 2], acc.z);
                atomicAdd(&sp[gcur * 16 + f4 + 3], acc.w);
                if (f4 == 0) atomicAdd(&sc[gcur], cacc);
            }
            gcur = gi; acc = make_float4(0.f, 0.f, 0.f, 0.f); cacc = 0.f;
        }
        ushort4_t hv = *(const ushort4_t*)&h_lds[(n - base) * 16 + f4];
        acc.x += bf2f(hv.x); acc.y += bf2f(hv.y);
        acc.z += bf2f(hv.z); acc.w += bf2f(hv.w);
        cacc += 1.f;
    }
    if (gcur >= 0) {
        atomicAdd(&sp[gcur * 16 + f4 + 0], acc.x);
        atomicAdd(&sp[gcur * 16 + f4 + 1], acc.y);
        atomicAdd(&sp[gcur * 16 + f4 + 2], acc.z);
        atomicAdd(&sp[gcur * 16 + f4 + 3], acc.w);
        if (f4 == 0) atomicAdd(&sc[gcur], cacc);
    }
    __syncthreads();
    for (int i = t; i < NG * 16; i += 256)
        if (sp[i] != 0.f) unsafeAtomicAdd(&pool[i], sp[i]);
    for (int i = t; i < NG; i += 256)
        if (sc[i] != 0.f) unsafeAtomicAdd(&cnt[i], sc[i]);
}

// ---------------- final linear head ----------------
__global__ void final_kernel(const float* __restrict__ pool, const float* __restrict__ cnt,
                             const float* __restrict__ lw, const float* __restrict__ lb,
                             float* __restrict__ out) {
    int idx = threadIdx.x;
    if (idx >= NG * 2) return;
    int g = idx >> 1;
    int c = idx & 1;
    float inv = 1.0f / fmaxf(cnt[g], 1.0f);
    float acc = 0.0f;
#pragma unroll
    for (int f = 0; f < 16; f++) acc += pool[g * 16 + f] * lw[c * 16 + f];
    out[idx] = acc * inv + lb[c];
}

extern "C" void kernel_launch(void* const* d_in, const int* in_sizes, int n_in,
                              void* d_out, int out_size, void* d_ws, size_t ws_size,
                              hipStream_t stream) {
    const float* x    = (const float*)d_in[0];
    const int*   ei   = (const int*)d_in[1];
    const int*   batch= (const int*)d_in[2];
    const float* W1 = (const float*)d_in[3];
    const float* b1 = (const float*)d_in[4];
    const float* g1 = (const float*)d_in[5];
    const float* be1= (const float*)d_in[6];
    const float* m1 = (const float*)d_in[7];
    const float* v1 = (const float*)d_in[8];
    const float* W2 = (const float*)d_in[9];
    const float* b2 = (const float*)d_in[10];
    const float* g2 = (const float*)d_in[11];
    const float* be2= (const float*)d_in[12];
    const float* m2 = (const float*)d_in[13];
    const float* v2 = (const float*)d_in[14];
    const float* W3 = (const float*)d_in[15];
    const float* b3 = (const float*)d_in[16];
    const float* g3 = (const float*)d_in[17];
    const float* be3= (const float*)d_in[18];
    const float* m3 = (const float*)d_in[19];
    const float* v3 = (const float*)d_in[20];
    const float* lw = (const float*)d_in[21];
    const float* lb = (const float*)d_in[22];

    const int* src = ei;            // edge_index[0]
    const int* dst = ei + NE;       // edge_index[1]

    float* ws = (float*)d_ws;
    // ---- workspace layout (4-byte units, 16B-aligned; ~62 MB total) ----
    size_t off = 0;
    int*   fill  = (int*)(ws + off); off += NN;    // in-degree / slot counters
    int*   deg_o = (int*)(ws + off); off += NN;    // out-degree
    float* pool  = ws + off; off += NG * 16;
    float* cnt   = ws + off; off += NG;
    size_t zero_bytes = off * sizeof(float);       // one memset covers all of the above
    float* rdeg  = ws + off; off += NN;            // rsqrt(deg_o) table
    int*   col   = (int*)(ws + off); off += (size_t)NN * CAP;  // fixed-stride CSR cols
    unsigned short* Tbf  = (unsigned short*)(ws + off); off += (size_t)NN * 32;  // NN*64 bf16
    unsigned short* Ubf  = (unsigned short*)(ws + off); off += (size_t)NN * 32;
    unsigned short* Bbbf = (unsigned short*)(ws + off); off += (size_t)NN * 32;
    unsigned short* S1bf = (unsigned short*)(ws + off); off += (size_t)NN * 32;  // S1 (w64)
    unsigned short* S2bf = (unsigned short*)(ws + off); off += (size_t)NN * 16;  // S2 (w32)
    unsigned short* S3bf = (unsigned short*)(ws + off); off += (size_t)NN * 8;   // S3 (w16)
    unsigned short* Bf1  = (unsigned short*)(ws + off); off += 12288;  // 24576 bf16
    unsigned short* Bf2  = (unsigned short*)(ws + off); off += 3072;   //  6144 bf16
    unsigned short* Bf3  = (unsigned short*)(ws + off); off += 768;    //  1536 bf16

    hipMemsetAsync(ws, 0, zero_bytes, stream);

    // ---- prepB first (stream-ordered: Bf1 complete before fused1's gemm blocks) ----
    prepB_all_kernel<<<16, BS, 0, stream>>>(W1, W2, W3, Bf1, Bf2, Bf3);

    // ---- fused: interleaved CSR scatter + gemm layer-1 ----
    fused1_kernel<<<NB_F1, 256, 0, stream>>>(
        src, dst, fill, deg_o, col, Bf1, x, Tbf, S1bf, Ubf, NE, NN);

    // ---- rsqrt(deg) table ----
    rdeg_kernel<<<cdiv(NN, BS), BS, 0, stream>>>(deg_o, rdeg, NN);

    // ---- layer 1 propA, then fused [propC1 + gemm2] ----
    propA8_kernel<64><<<cdiv((long long)NN * 8, BS), BS, 0, stream>>>(Ubf, Tbf, fill, rdeg,
                                                                      col, Bbbf, NN);
    propCG_kernel<64, 32><<<cdiv(NN, 64), 256, 0, stream>>>(
        Bbbf, S1bf, fill, rdeg, col, b1, g1, be1, m1, v1,
        Bf2, Tbf, S2bf, Ubf, NN);

    // ---- layer 2 propA, then fused [propC2 + gemm3] ----
    propA8_kernel<32><<<cdiv((long long)NN * 4, BS), BS, 0, stream>>>(Ubf, Tbf, fill, rdeg,
                                                                      col, Bbbf, NN);
    propCG_kernel<32, 16><<<cdiv(NN, 64), 256, 0, stream>>>(
        Bbbf, S2bf, fill, rdeg, col, b2, g2, be2, m2, v2,
        Bf3, Tbf, S3bf, Ubf, NN);

    // ---- layer 3 propA, then fused [propC3 + pool] ----
    propA8_kernel<16><<<cdiv((long long)NN * 2, BS), BS, 0, stream>>>(Ubf, Tbf, fill, rdeg,
                                                                      col, Bbbf, NN);
    poolC_kernel<<<cdiv(NN, PNPB), 256, 0, stream>>>(
        Bbbf, S3bf, fill, rdeg, col, b3, g3, be3, m3, v3,
        batch, pool, cnt, NN);

    // ---- head ----
    final_kernel<<<1, 128, 0, stream>>>(pool, cnt, lw, lb, (float*)d_out);
}

// Round 20
// 319.811 us; speedup vs baseline: 1.0641x; 1.0641x over previous
//
#include <hip/hip_runtime.h>
#include <hip/hip_bf16.h>

// Problem constants (match reference)
#define NN 100000   // nodes
#define NE 640000   // edges
#define NG 64       // graphs
#define BN_EPS 1e-5f

#define BS 256      // block size
#define PNPB 256    // nodes per block in pool
#define CAP 32      // fixed CSR slots per row (P(indeg>=32) ~ 1e-9; wrap-guarded)

// fused1: interleaved heterogeneous grid, 4 scatter : 5 gemm per 9-block group
// (R15-proven config). Lessons locked in: R16 (4-edge/thread scatter) regressed;
// R17 (head fusion w/ per-block device fences) cost 27us; R19 (4-wide predicated
// MLP gathers) cost 15us -- this file is the measured-optimal R18 configuration.
#define NB_SCAT 1250                 // cdiv(NE, 512)
#define NB_G1   1563
#define NB_F1   (313 * 9)            // 2817

typedef __attribute__((ext_vector_type(8))) unsigned short ushort8_t;
typedef __attribute__((ext_vector_type(4))) unsigned short ushort4_t;
typedef __attribute__((ext_vector_type(8))) short bf16x8_t;    // MFMA A/B frag (4 VGPR)
typedef __attribute__((ext_vector_type(4))) float floatx4_t;   // MFMA C/D frag

static inline int cdiv(long long a, int b) { return (int)((a + b - 1) / b); }

__device__ __forceinline__ float bf2f(unsigned short u) {
    union { unsigned int i; float f; } c; c.i = ((unsigned int)u) << 16; return c.f;
}
__device__ __forceinline__ unsigned short f2bf(float f) {   // RNE
    unsigned int u = __float_as_uint(f);
    u += 0x7fffu + ((u >> 16) & 1u);
    return (unsigned short)(u >> 16);
}

// ---- prepB piece: Bcat = [W2 | W1 | W0-W2] (FI x 3FO) in MFMA B-fragment layout ----
template <int FI, int FO>
__device__ __forceinline__ void prep_one(const float* __restrict__ W,
                                         unsigned short* __restrict__ Bfrag, int id) {
    constexpr int NS = FI / 32;
    int lane = id & 63;
    int s = (id >> 6) % NS;
    int t = (id >> 6) / NS;
    int n = t * 16 + (lane & 15);
    int kbase = s * 32 + (lane >> 4) * 8;
    int sec = n / FO;        // 0 -> W2, 1 -> W1, 2 -> W0 - W2
    int nc  = n % FO;
    ushort8_t out;
#pragma unroll
    for (int j = 0; j < 8; j++) {
        int k = kbase + j;
        float v;
        if (sec == 0)      v = W[(size_t)(2 * FI + k) * FO + nc];
        else if (sec == 1) v = W[(size_t)(1 * FI + k) * FO + nc];
        else               v = W[(size_t)(0 * FI + k) * FO + nc]
                             - W[(size_t)(2 * FI + k) * FO + nc];
        out[j] = f2bf(v);
    }
    *(ushort8_t*)(Bfrag + (size_t)id * 8) = out;
}

// Separate launch, stream-ordered BEFORE any consumer of Bf1/2/3 (R13 race lesson).
__global__ void prepB_all_kernel(const float* __restrict__ W1, const float* __restrict__ W2,
                                 const float* __restrict__ W3,
                                 unsigned short* __restrict__ Bf1,
                                 unsigned short* __restrict__ Bf2,
                                 unsigned short* __restrict__ Bf3) {
    int id = blockIdx.x * blockDim.x + threadIdx.x;
    if (id < 3072)      prep_one<128, 64>(W1, Bf1, id);            // 12*4*64
    else if (id < 3840) prep_one<64, 32>(W2, Bf2, id - 3072);      //  6*2*64
    else if (id < 4032) prep_one<32, 16>(W3, Bf3, id - 3840);      //  3*1*64
}

// ---- fused1: interleaved [scatter | gemm layer-1], NO LDS ----
__global__ __launch_bounds__(256) void fused1_kernel(
        const int* __restrict__ src, const int* __restrict__ dst,
        int* __restrict__ fill, int* __restrict__ deg_o, int* __restrict__ col,
        const unsigned short* __restrict__ Bf1,
        const float* __restrict__ x, unsigned short* __restrict__ Tbf,
        unsigned short* __restrict__ Sbf, unsigned short* __restrict__ Ubf,
        int E, int N) {
    const int g = blockIdx.x / 9;
    const int r = blockIdx.x % 9;
    if (r < 4) {
        // ------- scatter: 2 edges/thread (R15-proven) -------
        int sid = g * 4 + r;
        if (sid >= NB_SCAT) return;
        int e0 = (sid * 256 + threadIdx.x) * 2;
#pragma unroll
        for (int q = 0; q < 2; q++) {
            int e = e0 + q;
            if (e < E) {
                int s = src[e], d = dst[e];
                if (s != d) {
                    atomicAdd(&deg_o[s], 1);
                    int pos = atomicAdd(&fill[d], 1) & (CAP - 1);   // wrap guard
                    col[(size_t)d * CAP + pos] = s;
                }
            }
        }
        return;
    }
    // ------- gemm layer-1 path (direct-global B, latency hides in atomic shadow) -------
    int gblk = g * 5 + (r - 4);
    if (gblk >= NB_G1) return;
    constexpr int NT = 12;   // 3*64/16
    constexpr int NS = 4;    // 128/32
    const int lane = threadIdx.x & 63;
    const int wave = threadIdx.x >> 6;
    const int m0   = gblk * 64 + wave * 16;
    const int quad = lane >> 4;
    const int mrow = m0 + (lane & 15);

    floatx4_t acc[NT];
#pragma unroll
    for (int t = 0; t < NT; t++) acc[t] = (floatx4_t){0.f, 0.f, 0.f, 0.f};

#pragma unroll
    for (int s = 0; s < NS; s++) {
        bf16x8_t a;
        if (mrow < N) {
            const float* ap = x + (size_t)mrow * 128 + s * 32 + quad * 8;
            float4 a0 = *(const float4*)(ap);
            float4 a1 = *(const float4*)(ap + 4);
            a[0] = (short)f2bf(a0.x); a[1] = (short)f2bf(a0.y);
            a[2] = (short)f2bf(a0.z); a[3] = (short)f2bf(a0.w);
            a[4] = (short)f2bf(a1.x); a[5] = (short)f2bf(a1.y);
            a[6] = (short)f2bf(a1.z); a[7] = (short)f2bf(a1.w);
        } else {
            a = (bf16x8_t){0, 0, 0, 0, 0, 0, 0, 0};
        }
#pragma unroll
        for (int t = 0; t < NT; t++) {
            bf16x8_t b = *(const bf16x8_t*)(Bf1 + ((size_t)(t * NS + s) * 64 + lane) * 8);
            acc[t] = __builtin_amdgcn_mfma_f32_16x16x32_bf16(a, b, acc[t], 0, 0, 0);
        }
    }
    // C/D layout: col = lane&15, row = quad*4 + reg   [verified m89/m91]
#pragma unroll
    for (int t = 0; t < NT; t++) {
        int n   = t * 16 + (lane & 15);
        int sec = (t * 16) / 64;
        int nc  = n % 64;
#pragma unroll
        for (int r2 = 0; r2 < 4; r2++) {
            int m = m0 + quad * 4 + r2;
            if (m >= N) continue;
            unsigned short v = f2bf(acc[t][r2]);
            size_t o = (size_t)m * 64 + nc;
            if (sec == 0)      Ubf[o] = v;
            else if (sec == 1) Tbf[o] = v;
            else               Sbf[o] = v;
        }
    }
}

// ---- rdeg: rsqrt table so props do 1 mul/edge ----
__global__ void rdeg_kernel(const int* __restrict__ deg_o, float* __restrict__ rdeg, int N) {
    int i = blockIdx.x * blockDim.x + threadIdx.x;
    if (i < N) {
        int d = deg_o[i];
        rdeg[i] = (d > 0) ? rsqrtf((float)d) : 0.0f;
    }
}

// ---- propA8: Obf[i] = bf16( T[i] + 2 * sum_p w(p)*Ubf[col[p]] ), 2-way unrolled ----
template <int FO>
__global__ void propA8_kernel(const unsigned short* __restrict__ Ubf,
                              const unsigned short* __restrict__ Tbf,
                              const int* __restrict__ fill, const float* __restrict__ rdeg,
                              const int* __restrict__ col,
                              unsigned short* __restrict__ Obf, int N) {
    constexpr int PER = FO / 8;
    unsigned idx = blockIdx.x * blockDim.x + threadIdx.x;
    if (idx >= (unsigned)N * PER) return;
    int i = idx / PER;
    int c = (idx & (PER - 1)) * 8;
    int beg = i * CAP;
    int end = beg + min(fill[i], CAP);
    float di = -rdeg[i];
    float acc[8] = {0.f, 0.f, 0.f, 0.f, 0.f, 0.f, 0.f, 0.f};
    int p = beg;
    for (; p + 2 <= end; p += 2) {
        int s0 = col[p], s1 = col[p + 1];
        float w0 = di * rdeg[s0], w1 = di * rdeg[s1];
        ushort8_t u0 = *(const ushort8_t*)(Ubf + (size_t)s0 * FO + c);
        ushort8_t u1 = *(const ushort8_t*)(Ubf + (size_t)s1 * FO + c);
#pragma unroll
        for (int j = 0; j < 8; j++) {
            acc[j] = fmaf(w0, bf2f(u0[j]), acc[j]);
            acc[j] = fmaf(w1, bf2f(u1[j]), acc[j]);
        }
    }
    if (p < end) {
        int s0 = col[p];
        float w0 = di * rdeg[s0];
        ushort8_t u0 = *(const ushort8_t*)(Ubf + (size_t)s0 * FO + c);
#pragma unroll
        for (int j = 0; j < 8; j++) acc[j] = fmaf(w0, bf2f(u0[j]), acc[j]);
    }
    ushort8_t tv = *(const ushort8_t*)(Tbf + (size_t)i * FO + c);
    ushort8_t o;
#pragma unroll
    for (int j = 0; j < 8; j++) o[j] = f2bf(bf2f(tv[j]) + 2.f * acc[j]);
    *(ushort8_t*)(Obf + (size_t)i * FO + c) = o;
}

// ---- propCG<FI,FO>: fused [propC layer-k epilogue -> LDS h] + [gemm FI->FO] ----
template <int FI, int FO>
__global__ __launch_bounds__(256) void propCG_kernel(
        const unsigned short* __restrict__ Bbf,   // gather source (propA out), width FI
        const unsigned short* __restrict__ Sbf,   // local S term, width FI
        const int* __restrict__ fill, const float* __restrict__ rdeg,
        const int* __restrict__ col,
        const float* __restrict__ b, const float* __restrict__ g,
        const float* __restrict__ be, const float* __restrict__ m,
        const float* __restrict__ vv,
        const unsigned short* __restrict__ Bfrag,  // FI->FO fragments
        unsigned short* __restrict__ Tout, unsigned short* __restrict__ Sout,
        unsigned short* __restrict__ Uout, int N) {
    constexpr int PER = FI / 8;
    constexpr int NT = 3 * FO / 16;
    constexpr int NS = FI / 32;
    constexpr int NFRAG = NT * NS;
    constexpr int HST = FI + 8;     // h_lds row stride (shorts)
    __shared__ ushort8_t bl[NFRAG * 64];
    __shared__ unsigned short h_lds[64 * HST];

    for (int q = threadIdx.x; q < NFRAG * 64; q += 256)
        bl[q] = ((const ushort8_t*)Bfrag)[q];

    const int m0 = blockIdx.x * 64;

    // ---- phase 1: propC for rows m0..m0+63 -> h_lds ----
    for (int w = threadIdx.x; w < 64 * PER; w += 256) {
        int ii = w / PER;
        int i  = m0 + ii;
        int c  = (w % PER) * 8;
        ushort8_t o = (ushort8_t){0, 0, 0, 0, 0, 0, 0, 0};
        if (i < N) {
            int beg = i * CAP;
            int end = beg + min(fill[i], CAP);
            float di = -rdeg[i];
            float acc[8] = {0.f, 0.f, 0.f, 0.f, 0.f, 0.f, 0.f, 0.f};
            int p = beg;
            for (; p + 2 <= end; p += 2) {
                int s0 = col[p], s1 = col[p + 1];
                float w0 = di * rdeg[s0], w1 = di * rdeg[s1];
                ushort8_t u0 = *(const ushort8_t*)(Bbf + (size_t)s0 * FI + c);
                ushort8_t u1 = *(const ushort8_t*)(Bbf + (size_t)s1 * FI + c);
#pragma unroll
                for (int j = 0; j < 8; j++) {
                    acc[j] = fmaf(w0, bf2f(u0[j]), acc[j]);
                    acc[j] = fmaf(w1, bf2f(u1[j]), acc[j]);
                }
            }
            if (p < end) {
                int s0 = col[p];
                float w0 = di * rdeg[s0];
                ushort8_t u0 = *(const ushort8_t*)(Bbf + (size_t)s0 * FI + c);
#pragma unroll
                for (int j = 0; j < 8; j++) acc[j] = fmaf(w0, bf2f(u0[j]), acc[j]);
            }
            ushort8_t sv = *(const ushort8_t*)(Sbf + (size_t)i * FI + c);
#pragma unroll
            for (int j = 0; j < 8; j++) {
                int f = c + j;
                float A = g[f] * rsqrtf(vv[f] + BN_EPS);
                float B = be[f] - (m[f] - b[f]) * A;
                float y = (bf2f(sv[j]) + acc[j]) * A + B;
                y = y > 0.0f ? y : 0.01f * y;
                o[j] = f2bf(y);
            }
        }
        *(ushort8_t*)&h_lds[ii * HST + c] = o;
    }
    __syncthreads();

    // ---- phase 2: gemm FI->FO, A from h_lds ----
    const int lane = threadIdx.x & 63;
    const int wave = threadIdx.x >> 6;
    const int quad = lane >> 4;
    const int mloc = wave * 16 + (lane & 15);

    floatx4_t acc[NT];
#pragma unroll
    for (int t = 0; t < NT; t++) acc[t] = (floatx4_t){0.f, 0.f, 0.f, 0.f};

#pragma unroll
    for (int s = 0; s < NS; s++) {
        bf16x8_t a = *(const bf16x8_t*)&h_lds[mloc * HST + s * 32 + quad * 8];
#pragma unroll
        for (int t = 0; t < NT; t++) {
            bf16x8_t bfr = *(const bf16x8_t*)&bl[(t * NS + s) * 64 + lane];
            acc[t] = __builtin_amdgcn_mfma_f32_16x16x32_bf16(a, bfr, acc[t], 0, 0, 0);
        }
    }
#pragma unroll
    for (int t = 0; t < NT; t++) {
        int n   = t * 16 + (lane & 15);
        int sec = (t * 16) / FO;
        int nc  = n % FO;
#pragma unroll
        for (int r = 0; r < 4; r++) {
            int mm = m0 + wave * 16 + quad * 4 + r;
            if (mm >= N) continue;
            unsigned short v = f2bf(acc[t][r]);
            size_t o = (size_t)mm * FO + nc;
            if (sec == 0)      Uout[o] = v;
            else if (sec == 1) Tout[o] = v;
            else               Sout[o] = v;
        }
    }
}

// ---- poolC: fused [propC layer-3 (w16) -> LDS h3] + [mean pool] ----
__global__ __launch_bounds__(256) void poolC_kernel(
        const unsigned short* __restrict__ Bbf,   // propA<16> output
        const unsigned short* __restrict__ Sbf,   // S3
        const int* __restrict__ fill, const float* __restrict__ rdeg,
        const int* __restrict__ col,
        const float* __restrict__ b, const float* __restrict__ g,
        const float* __restrict__ be, const float* __restrict__ m,
        const float* __restrict__ vv,
        const int* __restrict__ batch,
        float* __restrict__ pool, float* __restrict__ cnt, int N) {
    __shared__ unsigned short h_lds[PNPB * 16];   // 8 KB
    __shared__ float sp[NG * 16];
    __shared__ float sc[NG];
    const int t = threadIdx.x;
    for (int i = t; i < NG * 16; i += 256) sp[i] = 0.f;
    for (int i = t; i < NG; i += 256) sc[i] = 0.f;

    const int base = blockIdx.x * PNPB;
    // ---- phase 1: propC<16> for rows base..base+255 -> h_lds ----
    for (int w = t; w < PNPB * 2; w += 256) {
        int ii = w >> 1;
        int i  = base + ii;
        int c  = (w & 1) * 8;
        ushort8_t o = (ushort8_t){0, 0, 0, 0, 0, 0, 0, 0};
        if (i < N) {
            int beg = i * CAP;
            int end = beg + min(fill[i], CAP);
            float di = -rdeg[i];
            float acc[8] = {0.f, 0.f, 0.f, 0.f, 0.f, 0.f, 0.f, 0.f};
            int p = beg;
            for (; p + 2 <= end; p += 2) {
                int s0 = col[p], s1 = col[p + 1];
                float w0 = di * rdeg[s0], w1 = di * rdeg[s1];
                ushort8_t u0 = *(const ushort8_t*)(Bbf + (size_t)s0 * 16 + c);
                ushort8_t u1 = *(const ushort8_t*)(Bbf + (size_t)s1 * 16 + c);
#pragma unroll
                for (int j = 0; j < 8; j++) {
                    acc[j] = fmaf(w0, bf2f(u0[j]), acc[j]);
                    acc[j] = fmaf(w1, bf2f(u1[j]), acc[j]);
                }
            }
            if (p < end) {
                int s0 = col[p];
                float w0 = di * rdeg[s0];
                ushort8_t u0 = *(const ushort8_t*)(Bbf + (size_t)s0 * 16 + c);
#pragma unroll
                for (int j = 0; j < 8; j++) acc[j] = fmaf(w0, bf2f(u0[j]), acc[j]);
            }
            ushort8_t sv = *(const ushort8_t*)(Sbf + (size_t)i * 16 + c);
#pragma unroll
            for (int j = 0; j < 8; j++) {
                int f = c + j;
                float A = g[f] * rsqrtf(vv[f] + BN_EPS);
                float B = be[f] - (m[f] - b[f]) * A;
                float y = (bf2f(sv[j]) + acc[j]) * A + B;
                y = y > 0.0f ? y : 0.01f * y;
                o[j] = f2bf(y);
            }
        }
        *(ushort8_t*)&h_lds[ii * 16 + c] = o;
    }
    __syncthreads();

    // ---- phase 2: pool from LDS ----
    const int f4 = (t & 3) * 4;      // feature quad
    const int nl = t >> 2;           // node lane 0..63
    const int nEnd = min(base + PNPB, N);
    float4 acc = make_float4(0.f, 0.f, 0.f, 0.f);
    float cacc = 0.f;
    int gcur = -1;
    for (int n = base + nl; n < nEnd; n += 64) {
        int gi = batch[n];
        if (gi != gcur) {
            if (gcur >= 0) {
                atomicAdd(&sp[gcur * 16 + f4 + 0], acc.x);
                atomicAdd(&sp[gcur * 16 + f4 + 1], acc.y);
                atomicAdd(&sp[gcur * 16 + f4 + 2], acc.z);
                atomicAdd(&sp[gcur * 16 + f4 + 3], acc.w);
                if (f4 == 0) atomicAdd(&sc[gcur], cacc);
            }
            gcur = gi; acc = make_float4(0.f, 0.f, 0.f, 0.f); cacc = 0.f;
        }
        ushort4_t hv = *(const ushort4_t*)&h_lds[(n - base) * 16 + f4];
        acc.x += bf2f(hv.x); acc.y += bf2f(hv.y);
        acc.z += bf2f(hv.z); acc.w += bf2f(hv.w);
        cacc += 1.f;
    }
    if (gcur >= 0) {
        atomicAdd(&sp[gcur * 16 + f4 + 0], acc.x);
        atomicAdd(&sp[gcur * 16 + f4 + 1], acc.y);
        atomicAdd(&sp[gcur * 16 + f4 + 2], acc.z);
        atomicAdd(&sp[gcur * 16 + f4 + 3], acc.w);
        if (f4 == 0) atomicAdd(&sc[gcur], cacc);
    }
    __syncthreads();
    for (int i = t; i < NG * 16; i += 256)
        if (sp[i] != 0.f) unsafeAtomicAdd(&pool[i], sp[i]);
    for (int i = t; i < NG; i += 256)
        if (sc[i] != 0.f) unsafeAtomicAdd(&cnt[i], sc[i]);
}

// ---------------- final linear head ----------------
__global__ void final_kernel(const float* __restrict__ pool, const float* __restrict__ cnt,
                             const float* __restrict__ lw, const float* __restrict__ lb,
                             float* __restrict__ out) {
    int idx = threadIdx.x;
    if (idx >= NG * 2) return;
    int g = idx >> 1;
    int c = idx & 1;
    float inv = 1.0f / fmaxf(cnt[g], 1.0f);
    float acc = 0.0f;
#pragma unroll
    for (int f = 0; f < 16; f++) acc += pool[g * 16 + f] * lw[c * 16 + f];
    out[idx] = acc * inv + lb[c];
}

extern "C" void kernel_launch(void* const* d_in, const int* in_sizes, int n_in,
                              void* d_out, int out_size, void* d_ws, size_t ws_size,
                              hipStream_t stream) {
    const float* x    = (const float*)d_in[0];
    const int*   ei   = (const int*)d_in[1];
    const int*   batch= (const int*)d_in[2];
    const float* W1 = (const float*)d_in[3];
    const float* b1 = (const float*)d_in[4];
    const float* g1 = (const float*)d_in[5];
    const float* be1= (const float*)d_in[6];
    const float* m1 = (const float*)d_in[7];
    const float* v1 = (const float*)d_in[8];
    const float* W2 = (const float*)d_in[9];
    const float* b2 = (const float*)d_in[10];
    const float* g2 = (const float*)d_in[11];
    const float* be2= (const float*)d_in[12];
    const float* m2 = (const float*)d_in[13];
    const float* v2 = (const float*)d_in[14];
    const float* W3 = (const float*)d_in[15];
    const float* b3 = (const float*)d_in[16];
    const float* g3 = (const float*)d_in[17];
    const float* be3= (const float*)d_in[18];
    const float* m3 = (const float*)d_in[19];
    const float* v3 = (const float*)d_in[20];
    const float* lw = (const float*)d_in[21];
    const float* lb = (const float*)d_in[22];

    const int* src = ei;            // edge_index[0]
    const int* dst = ei + NE;       // edge_index[1]

    float* ws = (float*)d_ws;
    // ---- workspace layout (4-byte units, 16B-aligned; ~62 MB total) ----
    size_t off = 0;
    int*   fill  = (int*)(ws + off); off += NN;    // in-degree / slot counters
    int*   deg_o = (int*)(ws + off); off += NN;    // out-degree
    float* pool  = ws + off; off += NG * 16;
    float* cnt   = ws + off; off += NG;
    size_t zero_bytes = off * sizeof(float);       // one memset covers all of the above
    float* rdeg  = ws + off; off += NN;            // rsqrt(deg_o) table
    int*   col   = (int*)(ws + off); off += (size_t)NN * CAP;  // fixed-stride CSR cols
    unsigned short* Tbf  = (unsigned short*)(ws + off); off += (size_t)NN * 32;  // NN*64 bf16
    unsigned short* Ubf  = (unsigned short*)(ws + off); off += (size_t)NN * 32;
    unsigned short* Bbbf = (unsigned short*)(ws + off); off += (size_t)NN * 32;
    unsigned short* S1bf = (unsigned short*)(ws + off); off += (size_t)NN * 32;  // S1 (w64)
    unsigned short* S2bf = (unsigned short*)(ws + off); off += (size_t)NN * 16;  // S2 (w32)
    unsigned short* S3bf = (unsigned short*)(ws + off); off += (size_t)NN * 8;   // S3 (w16)
    unsigned short* Bf1  = (unsigned short*)(ws + off); off += 12288;  // 24576 bf16
    unsigned short* Bf2  = (unsigned short*)(ws + off); off += 3072;   //  6144 bf16
    unsigned short* Bf3  = (unsigned short*)(ws + off); off += 768;    //  1536 bf16

    hipMemsetAsync(ws, 0, zero_bytes, stream);

    // ---- prepB first (stream-ordered: Bf1 complete before fused1's gemm blocks) ----
    prepB_all_kernel<<<16, BS, 0, stream>>>(W1, W2, W3, Bf1, Bf2, Bf3);

    // ---- fused: interleaved CSR scatter + gemm layer-1 ----
    fused1_kernel<<<NB_F1, 256, 0, stream>>>(
        src, dst, fill, deg_o, col, Bf1, x, Tbf, S1bf, Ubf, NE, NN);

    // ---- rsqrt(deg) table ----
    rdeg_kernel<<<cdiv(NN, BS), BS, 0, stream>>>(deg_o, rdeg, NN);

    // ---- layer 1 propA, then fused [propC1 + gemm2] ----
    propA8_kernel<64><<<cdiv((long long)NN * 8, BS), BS, 0, stream>>>(Ubf, Tbf, fill, rdeg,
                                                                      col, Bbbf, NN);
    propCG_kernel<64, 32><<<cdiv(NN, 64), 256, 0, stream>>>(
        Bbbf, S1bf, fill, rdeg, col, b1, g1, be1, m1, v1,
        Bf2, Tbf, S2bf, Ubf, NN);

    // ---- layer 2 propA, then fused [propC2 + gemm3] ----
    propA8_kernel<32><<<cdiv((long long)NN * 4, BS), BS, 0, stream>>>(Ubf, Tbf, fill, rdeg,
                                                                      col, Bbbf, NN);
    propCG_kernel<32, 16><<<cdiv(NN, 64), 256, 0, stream>>>(
        Bbbf, S2bf, fill, rdeg, col, b2, g2, be2, m2, v2,
        Bf3, Tbf, S3bf, Ubf, NN);

    // ---- layer 3 propA, then fused [propC3 + pool] ----
    propA8_kernel<16><<<cdiv((long long)NN * 2, BS), BS, 0, stream>>>(Ubf, Tbf, fill, rdeg,
                                                                      col, Bbbf, NN);
    poolC_kernel<<<cdiv(NN, PNPB), 256, 0, stream>>>(
        Bbbf, S3bf, fill, rdeg, col, b3, g3, be3, m3, v3,
        batch, pool, cnt, NN);

    // ---- head ----
    final_kernel<<<1, 128, 0, stream>>>(pool, cnt, lw, lb, (float*)d_out);
}